// Round 1
// baseline (30215.973 us; speedup 1.0000x reference)
//
#include <hip/hip_runtime.h>
#include <math.h>

#define T_STEPS 1000
#define BATCH   64
#define INSZ    700
#define NH      1000

// ---------------------------------------------------------------------------
// Kernel A: Z = X @ Win^T + bias  → written straight into d_out
//   A = x    : (M=64000, K=700) row-major
//   Bw = Win : (N=1000,  K=700) row-major
//   C        : (M, N) row-major
// 64x64 tile, BK=16, 256 threads, 4x4 micro-tile.
// ---------------------------------------------------------------------------
#define TM 64
#define TN 64
#define TK 16

__global__ __launch_bounds__(256) void proj_kernel(
    const float* __restrict__ A, const float* __restrict__ Bw,
    const float* __restrict__ bias, float* __restrict__ C)
{
    __shared__ float As[TK][68];   // [k][m], padded to 68 (float4-aligned, no bank pow2)
    __shared__ float Bs[TK][68];   // [k][n]

    const int tid = threadIdx.x;
    const int tx  = tid & 15;      // n micro index
    const int ty  = tid >> 4;      // m micro index
    const int m0  = blockIdx.y * TM;
    const int n0  = blockIdx.x * TN;

    // loader mapping: thread t loads row lr = t>>2, k-offset lk = (t&3)*4
    const int lr = tid >> 2;
    const int lk = (tid & 3) * 4;

    float acc[4][4] = {};

    for (int k0 = 0; k0 < INSZ; k0 += TK) {
        float4 av = make_float4(0.f, 0.f, 0.f, 0.f);
        if (k0 + lk < INSZ)   // rows of x are 700 floats; 700%4==0 so float4 ok
            av = *(const float4*)(A + (size_t)(m0 + lr) * INSZ + k0 + lk);
        As[lk + 0][lr] = av.x; As[lk + 1][lr] = av.y;
        As[lk + 2][lr] = av.z; As[lk + 3][lr] = av.w;

        float4 bv = make_float4(0.f, 0.f, 0.f, 0.f);
        if ((n0 + lr) < NH && (k0 + lk) < INSZ)
            bv = *(const float4*)(Bw + (size_t)(n0 + lr) * INSZ + k0 + lk);
        Bs[lk + 0][lr] = bv.x; Bs[lk + 1][lr] = bv.y;
        Bs[lk + 2][lr] = bv.z; Bs[lk + 3][lr] = bv.w;

        __syncthreads();

        #pragma unroll
        for (int k = 0; k < TK; ++k) {
            float4 a4 = *(const float4*)&As[k][ty * 4];
            float4 b4 = *(const float4*)&Bs[k][tx * 4];
            float a[4] = {a4.x, a4.y, a4.z, a4.w};
            float b[4] = {b4.x, b4.y, b4.z, b4.w};
            #pragma unroll
            for (int i = 0; i < 4; ++i)
                #pragma unroll
                for (int j = 0; j < 4; ++j)
                    acc[i][j] += a[i] * b[j];
        }
        __syncthreads();
    }

    #pragma unroll
    for (int i = 0; i < 4; ++i) {
        const int m = m0 + ty * 4 + i;
        #pragma unroll
        for (int j = 0; j < 4; ++j) {
            const int n = n0 + tx * 4 + j;
            if (n < NH)
                C[(size_t)m * NH + n] = acc[i][j] + bias[n];
        }
    }
}

// ---------------------------------------------------------------------------
// Kernel B (×1000): h_t = tanh(Z_t + h_{t-1} @ Wlsm), in-place on d_out[t].
// Grid: (16 n-chunks, 16 b-groups) × block (64, 4).
// Wave = 64 contiguous n → Wlsm row reads are 256B coalesced (L2-resident).
// 4 h rows staged in LDS; hS reads are wave-uniform b128 broadcasts.
// ---------------------------------------------------------------------------
__global__ __launch_bounds__(256) void step_kernel(
    const float* __restrict__ hprev,   // (B, N) = d_out + (t-1)*B*N
    const float* __restrict__ Wl,      // (N, N)
    float* __restrict__ zio,           // (B, N) = d_out + t*B*N  (in: Z, out: h)
    int first)
{
    __shared__ float hS[4][NH];

    const int lane = threadIdx.x;          // 0..63
    const int bi   = threadIdx.y;          // 0..3 (wave id)
    const int b    = blockIdx.y * 4 + bi;  // 0..63
    const int n    = blockIdx.x * 64 + lane;

    float acc = 0.f;
    if (!first) {
        // wave bi stages h row b: 250 float4 per row
        const float* hrow = hprev + (size_t)b * NH;
        for (int j = lane; j < 250; j += 64)
            *(float4*)&hS[bi][j * 4] = *(const float4*)(hrow + j * 4);
        __syncthreads();

        if (n < NH) {
            const float* wp = Wl + n;
            #pragma unroll 2
            for (int k = 0; k < NH; k += 4) {
                float4 h4 = *(const float4*)&hS[bi][k];
                acc += h4.x * wp[(size_t)(k + 0) * NH];
                acc += h4.y * wp[(size_t)(k + 1) * NH];
                acc += h4.z * wp[(size_t)(k + 2) * NH];
                acc += h4.w * wp[(size_t)(k + 3) * NH];
            }
        }
    }

    if (n < NH) {
        const size_t idx = (size_t)b * NH + n;
        const float z = zio[idx];
        zio[idx] = tanhf(z + acc);
    }
}

// ---------------------------------------------------------------------------
extern "C" void kernel_launch(void* const* d_in, const int* in_sizes, int n_in,
                              void* d_out, int out_size, void* d_ws, size_t ws_size,
                              hipStream_t stream) {
    const float* x    = (const float*)d_in[0];  // (T, B, INSZ)
    const float* Win  = (const float*)d_in[1];  // (N, INSZ)
    const float* bias = (const float*)d_in[2];  // (N,)
    const float* Wlsm = (const float*)d_in[3];  // (N, N)
    float* out = (float*)d_out;                 // (T, B, N)

    // Phase 1: input projection for all timesteps at once
    proj_kernel<<<dim3(16, (T_STEPS * BATCH) / TM), 256, 0, stream>>>(x, Win, bias, out);

    // Phase 2: sequential recurrence, one kernel per step, in-place on d_out
    for (int t = 0; t < T_STEPS; ++t) {
        const float* hprev = (t == 0) ? out : out + (size_t)(t - 1) * BATCH * NH;
        float* zio = out + (size_t)t * BATCH * NH;
        step_kernel<<<dim3(16, 16), dim3(64, 4), 0, stream>>>(hprev, Wlsm, zio, t == 0);
    }
}

// Round 2
// 16792.531 us; speedup vs baseline: 1.7994x; 1.7994x over previous
//
#include <hip/hip_runtime.h>
#include <math.h>

#define T_STEPS 1000
#define BATCH   64
#define INSZ    700
#define NH      1000

// ---------------------------------------------------------------------------
// Kernel A: Z = X @ Win^T + bias  → written straight into d_out
//   A = x (M=64000, K=700) row-major; Bw = Win (N=1000, K=700) row-major.
// 64x64 tile, BK=16, 256 threads, 4x4 micro-tile. (unchanged from R1)
// ---------------------------------------------------------------------------
#define TM 64
#define TN 64
#define TK 16

__global__ __launch_bounds__(256) void proj_kernel(
    const float* __restrict__ A, const float* __restrict__ Bw,
    const float* __restrict__ bias, float* __restrict__ C)
{
    __shared__ float As[TK][68];
    __shared__ float Bs[TK][68];

    const int tid = threadIdx.x;
    const int tx  = tid & 15;
    const int ty  = tid >> 4;
    const int m0  = blockIdx.y * TM;
    const int n0  = blockIdx.x * TN;

    const int lr = tid >> 2;
    const int lk = (tid & 3) * 4;

    float acc[4][4] = {};

    for (int k0 = 0; k0 < INSZ; k0 += TK) {
        float4 av = make_float4(0.f, 0.f, 0.f, 0.f);
        if (k0 + lk < INSZ)
            av = *(const float4*)(A + (size_t)(m0 + lr) * INSZ + k0 + lk);
        As[lk + 0][lr] = av.x; As[lk + 1][lr] = av.y;
        As[lk + 2][lr] = av.z; As[lk + 3][lr] = av.w;

        float4 bv = make_float4(0.f, 0.f, 0.f, 0.f);
        if ((n0 + lr) < NH && (k0 + lk) < INSZ)
            bv = *(const float4*)(Bw + (size_t)(n0 + lr) * INSZ + k0 + lk);
        Bs[lk + 0][lr] = bv.x; Bs[lk + 1][lr] = bv.y;
        Bs[lk + 2][lr] = bv.z; Bs[lk + 3][lr] = bv.w;

        __syncthreads();

        #pragma unroll
        for (int k = 0; k < TK; ++k) {
            float4 a4 = *(const float4*)&As[k][ty * 4];
            float4 b4 = *(const float4*)&Bs[k][tx * 4];
            float a[4] = {a4.x, a4.y, a4.z, a4.w};
            float b[4] = {b4.x, b4.y, b4.z, b4.w};
            #pragma unroll
            for (int i = 0; i < 4; ++i)
                #pragma unroll
                for (int j = 0; j < 4; ++j)
                    acc[i][j] += a[i] * b[j];
        }
        __syncthreads();
    }

    #pragma unroll
    for (int i = 0; i < 4; ++i) {
        const int m = m0 + ty * 4 + i;
        #pragma unroll
        for (int j = 0; j < 4; ++j) {
            const int n = n0 + tx * 4 + j;
            if (n < NH)
                C[(size_t)m * NH + n] = acc[i][j] + bias[n];
        }
    }
}

// ---------------------------------------------------------------------------
// Kernel B (×1000): h_t = tanh(Z_t + h_{t-1} @ Wlsm), in-place on d_out[t].
//
// Grid 252 = (63 n-slabs of 16) × (4 b-quarters of 16). Block 512 = 8 waves.
// Wave w owns k ∈ [128w, min(128w+128,1000)) — 8-way split-k, LDS-reduced.
// Lane → (b = b0 + lane&15, n-quad = n0 + (lane>>4)*4): acc[4] per thread.
// Per 4k-iter: 1 h float4 (16 rows, L1-amortized) + 4 W row loads (each a
// single 64B line: lanes sharing b read consecutive n) + 16 FMAs → VALU-bound.
// W traffic/WG = 8 KB/wave ×8 = 64 KB (read once); h traffic/WG = 64 KB.
// ---------------------------------------------------------------------------
__global__ __launch_bounds__(512) void step_kernel(
    const float* __restrict__ hprev,   // (B, N) = d_out + (t-1)*B*N
    const float* __restrict__ Wl,      // (N, N) row-major
    float* __restrict__ zio,           // (B, N) = d_out + t*B*N (in: Z, out: h)
    int first)
{
    __shared__ float red[8][64][4];

    const int tid  = threadIdx.x;
    const int w    = tid >> 6;        // wave 0..7 → k-chunk
    const int lane = tid & 63;
    const int wg   = blockIdx.x;
    const int bq   = wg & 3;          // b-quarter
    const int ns   = wg >> 2;         // n-slab 0..62
    const int b    = bq * 16 + (lane & 15);
    const int nq   = lane >> 4;       // 0..3
    const int n    = ns * 16 + nq * 4;
    const int nc   = (n > 996) ? 996 : n;   // clamp so tail loads stay in-bounds

    float4 acc = make_float4(0.f, 0.f, 0.f, 0.f);

    if (!first) {
        const float* hrow = hprev + (size_t)b * NH;
        const int k0 = w * 128;
        const int k1 = (k0 + 128 < NH) ? (k0 + 128) : NH;   // wave 7: 104 k
        #pragma unroll 2
        for (int k = k0; k < k1; k += 4) {
            const float4 h4 = *(const float4*)(hrow + k);
            const float4 w0 = *(const float4*)(Wl + (size_t)(k + 0) * NH + nc);
            const float4 w1 = *(const float4*)(Wl + (size_t)(k + 1) * NH + nc);
            const float4 w2 = *(const float4*)(Wl + (size_t)(k + 2) * NH + nc);
            const float4 w3 = *(const float4*)(Wl + (size_t)(k + 3) * NH + nc);
            acc.x += h4.x * w0.x; acc.y += h4.x * w0.y;
            acc.z += h4.x * w0.z; acc.w += h4.x * w0.w;
            acc.x += h4.y * w1.x; acc.y += h4.y * w1.y;
            acc.z += h4.y * w1.z; acc.w += h4.y * w1.w;
            acc.x += h4.z * w2.x; acc.y += h4.z * w2.y;
            acc.z += h4.z * w2.z; acc.w += h4.z * w2.w;
            acc.x += h4.w * w3.x; acc.y += h4.w * w3.y;
            acc.z += h4.w * w3.z; acc.w += h4.w * w3.w;
        }
    }

    *(float4*)&red[w][lane][0] = acc;
    __syncthreads();

    if (tid < 256) {
        const int l = tid & 63;
        const int j = tid >> 6;
        float s = red[0][l][j] + red[1][l][j] + red[2][l][j] + red[3][l][j]
                + red[4][l][j] + red[5][l][j] + red[6][l][j] + red[7][l][j];
        const int bo = bq * 16 + (l & 15);
        const int no = ns * 16 + (l >> 4) * 4 + j;
        if (no < NH) {
            const size_t idx = (size_t)bo * NH + no;
            zio[idx] = tanhf(zio[idx] + s);
        }
    }
}

// ---------------------------------------------------------------------------
extern "C" void kernel_launch(void* const* d_in, const int* in_sizes, int n_in,
                              void* d_out, int out_size, void* d_ws, size_t ws_size,
                              hipStream_t stream) {
    const float* x    = (const float*)d_in[0];  // (T, B, INSZ)
    const float* Win  = (const float*)d_in[1];  // (N, INSZ)
    const float* bias = (const float*)d_in[2];  // (N,)
    const float* Wlsm = (const float*)d_in[3];  // (N, N)
    float* out = (float*)d_out;                 // (T, B, N)

    // Phase 1: input projection for all timesteps at once
    proj_kernel<<<dim3(16, (T_STEPS * BATCH) / TM), 256, 0, stream>>>(x, Win, bias, out);

    // Phase 2: sequential recurrence, one kernel per step, in-place on d_out
    for (int t = 0; t < T_STEPS; ++t) {
        const float* hprev = (t == 0) ? out : out + (size_t)(t - 1) * BATCH * NH;
        float* zio = out + (size_t)t * BATCH * NH;
        step_kernel<<<dim3(252), 512, 0, stream>>>(hprev, Wlsm, zio, t == 0);
    }
}